// Round 6
// baseline (335.424 us; speedup 1.0000x reference)
//
#include <hip/hip_runtime.h>

#define B 8
#define N 2048
#define FIN 10
#define D 128
#define ALPHA 0.02f
#define LOG2E 1.44269504088896340736f
#define BR 32     // rows per block, k_proj
#define NBLK_ATTN 1024

typedef short bf8 __attribute__((ext_vector_type(8)));   // 8 bf16 in 4 VGPRs
typedef short s4v __attribute__((ext_vector_type(4)));
typedef float f32x4 __attribute__((ext_vector_type(4)));
typedef unsigned u4v __attribute__((ext_vector_type(4)));

__device__ __forceinline__ float lrelu(float x) { return x >= 0.f ? x : ALPHA * x; }

// f32 -> bf16 RNE (weights/Wh only)
__device__ __forceinline__ short f2b(float f) {
    unsigned u = __float_as_uint(f);
    return (short)((u + 0x7fffu + ((u >> 16) & 1u)) >> 16);
}

__device__ __forceinline__ float fexp2(float x) {
#if __has_builtin(__builtin_amdgcn_exp2f)
    return __builtin_amdgcn_exp2f(x);
#else
    return exp2f(x);
#endif
}

// pack two f32 -> two bf16 (truncation) in one v_perm
__device__ __forceinline__ unsigned pack2(float lo, float hi) {
#if __has_builtin(__builtin_amdgcn_perm)
    return __builtin_amdgcn_perm(__float_as_uint(hi), __float_as_uint(lo), 0x07060302u);
#else
    return (__float_as_uint(hi) & 0xFFFF0000u) | (__float_as_uint(lo) >> 16);
#endif
}

__device__ __forceinline__ unsigned enc_key(float v) {
    unsigned b = __float_as_uint(v);
    return (b & 0x80000000u) ? ~b : (b | 0x80000000u);
}
__device__ __forceinline__ float dec_key(unsigned k) {
    unsigned b = (k & 0x80000000u) ? (k & 0x7fffffffu) : ~k;
    return __uint_as_float(b);
}

// ---------------------------------------------------------------------------
// k_prep: one-time Wg fp32->bf16 (RNE) + zero-init pooled/cnt.
// ---------------------------------------------------------------------------
__global__ __launch_bounds__(256) void k_prep(
    const float* __restrict__ Wg, unsigned short* __restrict__ Wgb,
    unsigned* __restrict__ pooled, unsigned* __restrict__ cnt)
{
    const int g = blockIdx.x * 256 + threadIdx.x;    // 0..4095
    float4 f = *(const float4*)&Wg[g * 4];
    s4v v;
    v[0] = f2b(f.x); v[1] = f2b(f.y); v[2] = f2b(f.z); v[3] = f2b(f.w);
    *(s4v*)&Wgb[g * 4] = v;
    if (g < B * D) pooled[g] = 0u;
    if (g == B * D) *cnt = 0u;
}

// ---------------------------------------------------------------------------
// k_proj: x = lrelu(LN(h@W1^T+b1)) [bf16] ; Wh = x@Wg^T+bg via MFMA (fp32 acc);
// emits WhT bf16 [d][j] + e1,e2 (exp2-domain) fp32.
// Block = 32 rows, 256 threads (4 waves). Grid = 512.
// ---------------------------------------------------------------------------
__global__ __launch_bounds__(256) void k_proj(
    const float* __restrict__ h, const float* __restrict__ W1, const float* __restrict__ b1,
    const unsigned short* __restrict__ Wgb, const float* __restrict__ bg,
    const float* __restrict__ a1, const float* __restrict__ a2,
    unsigned short* __restrict__ WhT, float* __restrict__ e1g, float* __restrict__ e2g)
{
    __shared__ __align__(16) short xep_lds[32 * 136];
    __shared__ __align__(16) short wg_lds[D * 136];
    __shared__ float W1_lds[D * 11];
    __shared__ float h_lds[BR * FIN];
    __shared__ float ep1[2][BR], ep2[2][BR];

    const int t = threadIdx.x;
    const int r0 = blockIdx.x * BR;
    const int bb = r0 >> 11;
    const int jloc = r0 & (N - 1);

    for (int idx = t; idx < D * FIN; idx += 256)
        W1_lds[(idx / FIN) * 11 + (idx % FIN)] = W1[idx];
    for (int idx = t; idx < BR * FIN; idx += 256)
        h_lds[idx] = h[(size_t)r0 * FIN + idx];
    __syncthreads();

    // stage pre-converted Wg bf16 -> LDS (straight copy)
    {
        const int dr = t >> 4;
        const int j8 = t & 15;
        #pragma unroll
        for (int pass = 0; pass < 8; pass++) {
            int dd = pass * 16 + dr;
            *(bf8*)&wg_lds[dd * 136 + j8 * 8] = *(const bf8*)&Wgb[dd * D + j8 * 8];
        }
    }

    // phase 1: fc1 + LN + lrelu — all 8 rows hoisted for ILP
    const int w = t >> 6, lane = t & 63;
    {
        float b1v0 = b1[lane], b1v1 = b1[lane + 64];
        float sA[8], sB[8], smv[8], sqv[8];
        #pragma unroll
        for (int i = 0; i < 8; i++) {
            const float* hr = &h_lds[(w * 8 + i) * FIN];
            float s0 = b1v0, s1 = b1v1;
            #pragma unroll
            for (int k = 0; k < FIN; k++) {
                float hv = hr[k];
                s0 += hv * W1_lds[lane * 11 + k];
                s1 += hv * W1_lds[(lane + 64) * 11 + k];
            }
            sA[i] = s0; sB[i] = s1;
            smv[i] = s0 + s1; sqv[i] = s0 * s0 + s1 * s1;
        }
        #pragma unroll
        for (int m = 1; m <= 32; m <<= 1) {
            #pragma unroll
            for (int i = 0; i < 8; i++) { smv[i] += __shfl_xor(smv[i], m); sqv[i] += __shfl_xor(sqv[i], m); }
        }
        #pragma unroll
        for (int i = 0; i < 8; i++) {
            int r = w * 8 + i;
            float mean = smv[i] * (1.f / D);
            float var  = sqv[i] * (1.f / D) - mean * mean;
            float rs = rsqrtf(var + 1e-5f);
            xep_lds[r * 136 + lane]      = f2b(lrelu((sA[i] - mean) * rs));
            xep_lds[r * 136 + lane + 64] = f2b(lrelu((sB[i] - mean) * rs));
        }
    }
    __syncthreads();

    // phase 2: MFMA  Wh[32][128] = x @ Wg^T
    const int l15 = lane & 15, q = lane >> 4;
    const int mw = w & 1, np = w >> 1;
    f32x4 acc[4];
    #pragma unroll
    for (int nt = 0; nt < 4; nt++)
        #pragma unroll
        for (int r = 0; r < 4; r++) acc[nt][r] = 0.f;

    #pragma unroll
    for (int ks = 0; ks < 4; ks++) {
        bf8 av = *(const bf8*)&xep_lds[(mw * 16 + l15) * 136 + ks * 32 + q * 8];
        #pragma unroll
        for (int nt = 0; nt < 4; nt++) {
            bf8 bv = *(const bf8*)&wg_lds[((np * 4 + nt) * 16 + l15) * 136 + ks * 32 + q * 8];
            acc[nt] = __builtin_amdgcn_mfma_f32_16x16x32_bf16(av, bv, acc[nt], 0, 0, 0);
        }
    }

    // epilogue: +bg, e1/e2 partials
    float e1p[4] = {0.f, 0.f, 0.f, 0.f}, e2p[4] = {0.f, 0.f, 0.f, 0.f};
    #pragma unroll
    for (int nt = 0; nt < 4; nt++) {
        int col = (np * 4 + nt) * 16 + l15;
        float bgv = bg[col], a1v = a1[col], a2v = a2[col];
        #pragma unroll
        for (int r = 0; r < 4; r++) {
            float v = acc[nt][r] + bgv;
            acc[nt][r] = v;
            e1p[r] += v * a1v;
            e2p[r] += v * a2v;
        }
    }
    #pragma unroll
    for (int m = 1; m <= 8; m <<= 1) {
        #pragma unroll
        for (int r = 0; r < 4; r++) { e1p[r] += __shfl_xor(e1p[r], m); e2p[r] += __shfl_xor(e2p[r], m); }
    }
    if (l15 == 0) {
        #pragma unroll
        for (int r = 0; r < 4; r++) {
            ep1[np][mw * 16 + q * 4 + r] = e1p[r];
            ep2[np][mw * 16 + q * 4 + r] = e2p[r];
        }
    }
    __syncthreads();
    if (t < BR) {
        e1g[r0 + t] = (ep1[0][t] + ep1[1][t]) * LOG2E;
        e2g[r0 + t] = (ep2[0][t] + ep2[1][t]) * LOG2E;
    }
    #pragma unroll
    for (int nt = 0; nt < 4; nt++) {
        int col = (np * 4 + nt) * 16 + l15;
        #pragma unroll
        for (int r = 0; r < 4; r++)
            xep_lds[col * 36 + mw * 16 + q * 4 + r] = f2b(acc[nt][r]);
    }
    __syncthreads();
    {
        const int col = t >> 1, jh = (t & 1) * 16;
        unsigned short* dst = WhT + ((size_t)(bb * D + col)) * N + jloc + jh;
        #pragma unroll
        for (int i2 = 0; i2 < 4; i2++)
            *(uint2*)(dst + i2 * 4) = *(const uint2*)&xep_lds[col * 36 + jh + i2 * 4];
    }
}

// ---------------------------------------------------------------------------
// k_attn v4: barrier-free K-loop + 4-way work split for TLP.
// Block = one 16-row tile, 4 waves: wave = (ds = D-half, js = j-half).
// Each wave: cols [ds*64, +64), j in [js*1024, +1024), 32 chunks of 32 j.
// MFMA fragments built directly from global loads (no LDS in K-loop).
// Epilogue: cross-wave O/l reduction in LDS, LN, lrelu, max-pool.
// Grid (N/16, B) = 1024 blocks x 256 threads -> 16 waves/CU.
// ---------------------------------------------------------------------------
struct Stage {
    int4 a0, a1;          // adj[i0+l15][jbase + c*32 + q*8 + 0..7]
    float4 e20, e21;      // e2[jbase + c*32 + q*8 + 0..7]
    bf8 wv[4];            // WhT[ds*64+nt*16+l15][jbase + c*32 + q*8 + 0..7]
};

__device__ __forceinline__ void load_stage(Stage& s, const int* adjp,
        const float* e2p, const unsigned short* whp, int c) {
    const int off = c * 32;
    s.a0  = *(const int4*)(adjp + off);
    s.a1  = *(const int4*)(adjp + off + 4);
    s.e20 = *(const float4*)(e2p + off);
    s.e21 = *(const float4*)(e2p + off + 4);
    #pragma unroll
    for (int nt = 0; nt < 4; nt++)
        s.wv[nt] = *(const bf8*)(whp + (size_t)nt * 16 * N + off);
}

__device__ __forceinline__ void consume(const Stage& s, float e1v,
        f32x4* acc, f32x4& accl, bf8 ones) {
    float t0 = e1v + s.e20.x, t1 = e1v + s.e20.y, t2 = e1v + s.e20.z, t3 = e1v + s.e20.w;
    float t4 = e1v + s.e21.x, t5 = e1v + s.e21.y, t6 = e1v + s.e21.z, t7 = e1v + s.e21.w;
    float p0 = s.a0.x ? fexp2(fmaxf(t0, ALPHA * t0)) : 0.f;
    float p1 = s.a0.y ? fexp2(fmaxf(t1, ALPHA * t1)) : 0.f;
    float p2 = s.a0.z ? fexp2(fmaxf(t2, ALPHA * t2)) : 0.f;
    float p3 = s.a0.w ? fexp2(fmaxf(t3, ALPHA * t3)) : 0.f;
    float p4 = s.a1.x ? fexp2(fmaxf(t4, ALPHA * t4)) : 0.f;
    float p5 = s.a1.y ? fexp2(fmaxf(t5, ALPHA * t5)) : 0.f;
    float p6 = s.a1.z ? fexp2(fmaxf(t6, ALPHA * t6)) : 0.f;
    float p7 = s.a1.w ? fexp2(fmaxf(t7, ALPHA * t7)) : 0.f;
    u4v uu;
    uu.x = pack2(p0, p1); uu.y = pack2(p2, p3);
    uu.z = pack2(p4, p5); uu.w = pack2(p6, p7);
    bf8 av = *(bf8*)&uu;
    #pragma unroll
    for (int nt = 0; nt < 4; nt++)
        acc[nt] = __builtin_amdgcn_mfma_f32_16x16x32_bf16(av, s.wv[nt], acc[nt], 0, 0, 0);
    accl = __builtin_amdgcn_mfma_f32_16x16x32_bf16(av, ones, accl, 0, 0, 0);
}

__global__ __launch_bounds__(256) void k_attn(
    const int* __restrict__ adj, const unsigned short* __restrict__ WhT,
    const float* __restrict__ e1g, const float* __restrict__ e2g,
    unsigned* __restrict__ pooled, unsigned* __restrict__ cnt,
    const float* __restrict__ W2, const float* __restrict__ b2,
    float* __restrict__ out)
{
    __shared__ float ored[2][16][132];     // [js][row][col] partial O, 16.9 KB
    __shared__ float lred[2][16];          // [js][row] partial l
    __shared__ int finalflag;

    const int t = threadIdx.x;
    const int w = t >> 6, lane = t & 63;
    const int l15 = lane & 15, q = lane >> 4;
    const int ds = w >> 1;                 // D-half: cols [ds*64, +64)
    const int js = w & 1;                  // j-half: [js*1024, +1024)
    const int b = blockIdx.y;
    const int i0 = blockIdx.x * 16;

    const float e1v = e1g[b * N + i0 + l15];    // exp2-domain

    const int jb = js * (N / 2);
    const int* adjp = adj + ((size_t)b * N + i0 + l15) * N + jb + q * 8;
    const float* e2p = e2g + b * N + jb + q * 8;
    const unsigned short* whp = WhT + ((size_t)b * D + ds * 64 + l15) * N + jb + q * 8;

    f32x4 acc[4], accl;
    #pragma unroll
    for (int nt = 0; nt < 4; nt++)
        #pragma unroll
        for (int r = 0; r < 4; r++) acc[nt][r] = 0.f;
    #pragma unroll
    for (int r = 0; r < 4; r++) accl[r] = 0.f;

    bf8 ones;
    #pragma unroll
    for (int i = 0; i < 8; i++) ones[i] = (short)0x3F80;

    Stage SA, SB;
    load_stage(SA, adjp, e2p, whp, 0);
    load_stage(SB, adjp, e2p, whp, 1);

    for (int c = 0; c < 32; c += 2) {
        consume(SA, e1v, acc, accl, ones);
        if (c + 2 < 32) load_stage(SA, adjp, e2p, whp, c + 2);
        consume(SB, e1v, acc, accl, ones);
        if (c + 3 < 32) load_stage(SB, adjp, e2p, whp, c + 3);
    }

    // write partial O and l to LDS
    #pragma unroll
    for (int nt = 0; nt < 4; nt++) {
        int col = ds * 64 + nt * 16 + l15;
        #pragma unroll
        for (int r = 0; r < 4; r++)
            ored[js][q * 4 + r][col] = acc[nt][r];
    }
    if (ds == 0 && l15 == 0) {
        #pragma unroll
        for (int r = 0; r < 4; r++) lred[js][q * 4 + r] = accl[r];
    }
    __syncthreads();

    // reduce + LN + lrelu; thread -> (row rr = t>>4, cols (t&15)*8..+8)
    const int rr = t >> 4, cg = (t & 15) * 8;
    float v[8];
    float linv = 1.f / (lred[0][rr] + lred[1][rr]);
    float sm = 0.f, sq = 0.f;
    #pragma unroll
    for (int k = 0; k < 8; k++) {
        float o = (ored[0][rr][cg + k] + ored[1][rr][cg + k]) * linv;
        v[k] = o;
        sm += o; sq += o * o;
    }
    #pragma unroll
    for (int m = 1; m <= 8; m <<= 1) { sm += __shfl_xor(sm, m); sq += __shfl_xor(sq, m); }
    {
        float mean = sm * (1.f / D);
        float var  = sq * (1.f / D) - mean * mean;
        float rs = rsqrtf(var + 1e-5f);
        #pragma unroll
        for (int k = 0; k < 8; k++)
            ored[0][rr][cg + k] = lrelu((v[k] - mean) * rs);   // in-place: same slots this thread read
    }
    __syncthreads();

    // column max over 16 rows -> atomicMax into pooled
    if (t < D) {
        float mxv = ored[0][0][t];
        #pragma unroll
        for (int r = 1; r < 16; r++) mxv = fmaxf(mxv, ored[0][r][t]);
        atomicMax(&pooled[b * D + t], enc_key(mxv));
    }
    __syncthreads();

    // completion counter; last block does final 128->2 matmul + log_softmax
    if (t == 0) {
        __threadfence();
        unsigned old = atomicAdd(cnt, 1u);
        finalflag = (old == NBLK_ATTN - 1) ? 1 : 0;
    }
    __syncthreads();
    if (finalflag) {
        const int fb = t >> 5;
        const int fq = t & 31;
        float s0 = 0.f, s1 = 0.f;
        #pragma unroll
        for (int m = 0; m < 4; m++) {
            int dd = fq + 32 * m;
            unsigned key = __hip_atomic_load(&pooled[fb * D + dd], __ATOMIC_RELAXED,
                                             __HIP_MEMORY_SCOPE_AGENT);
            float vv = dec_key(key);
            s0 += vv * W2[dd];
            s1 += vv * W2[D + dd];
        }
        #pragma unroll
        for (int m = 1; m <= 16; m <<= 1) { s0 += __shfl_xor(s0, m); s1 += __shfl_xor(s1, m); }
        if (fq == 0) {
            float o0 = s0 + b2[0], o1 = s1 + b2[1];
            float mxv = fmaxf(o0, o1);
            float ls = logf(__expf(o0 - mxv) + __expf(o1 - mxv));
            out[fb * 2 + 0] = o0 - mxv - ls;
            out[fb * 2 + 1] = o1 - mxv - ls;
        }
    }
}

extern "C" void kernel_launch(void* const* d_in, const int* in_sizes, int n_in,
                              void* d_out, int out_size, void* d_ws, size_t ws_size,
                              hipStream_t stream) {
    const float* h   = (const float*)d_in[0];
    const int*   adj = (const int*)d_in[1];
    const float* W1  = (const float*)d_in[2];
    const float* b1  = (const float*)d_in[3];
    const float* Wg  = (const float*)d_in[4];
    const float* bg  = (const float*)d_in[5];
    const float* a1  = (const float*)d_in[6];
    const float* a2  = (const float*)d_in[7];
    const float* W2  = (const float*)d_in[8];
    const float* b2  = (const float*)d_in[9];
    float* out = (float*)d_out;

    unsigned short* WhT = (unsigned short*)d_ws;                       // B*D*N bf16
    float* e1g = (float*)((char*)d_ws + (size_t)B * D * N * 2);        // B*N f32
    float* e2g = e1g + (size_t)B * N;                                  // B*N f32
    unsigned* pooled = (unsigned*)(e2g + (size_t)B * N);               // B*D u32
    unsigned* cnt = pooled + (size_t)B * D;                            // 1 u32
    unsigned short* Wgb = (unsigned short*)(cnt + 4);                  // D*D bf16

    k_prep<<<16, 256, 0, stream>>>(Wg, Wgb, pooled, cnt);
    k_proj<<<(B * N) / BR, 256, 0, stream>>>(h, W1, b1, Wgb, bg, a1, a2,
                                             WhT, e1g, e2g);
    k_attn<<<dim3(N / 16, B), 256, 0, stream>>>(adj, WhT, e1g, e2g, pooled, cnt,
                                                W2, b2, out);
}

// Round 7
// 243.534 us; speedup vs baseline: 1.3773x; 1.3773x over previous
//
#include <hip/hip_runtime.h>

#define B 8
#define N 2048
#define FIN 10
#define D 128
#define ALPHA 0.02f
#define LOG2E 1.44269504088896340736f
#define BR 32     // rows per block, k_proj
#define TI 32     // rows per block, k_attn
#define JC 128    // j-chunk, k_attn
#define NBLK_ATTN ((N / TI) * B)   // 512

typedef short bf8 __attribute__((ext_vector_type(8)));   // 8 bf16 in 4 VGPRs
typedef short s4v __attribute__((ext_vector_type(4)));
typedef float f32x4 __attribute__((ext_vector_type(4)));

__device__ __forceinline__ float lrelu(float x) { return x >= 0.f ? x : ALPHA * x; }

// f32 -> bf16 RNE (weights/Wh only)
__device__ __forceinline__ short f2b(float f) {
    unsigned u = __float_as_uint(f);
    return (short)((u + 0x7fffu + ((u >> 16) & 1u)) >> 16);
}

__device__ __forceinline__ float fexp2(float x) {
#if __has_builtin(__builtin_amdgcn_exp2f)
    return __builtin_amdgcn_exp2f(x);
#else
    return exp2f(x);
#endif
}

// pack two f32 -> two bf16 (truncation) in one v_perm
__device__ __forceinline__ unsigned pack2(float lo, float hi) {
#if __has_builtin(__builtin_amdgcn_perm)
    return __builtin_amdgcn_perm(__float_as_uint(hi), __float_as_uint(lo), 0x07060302u);
#else
    return (__float_as_uint(hi) & 0xFFFF0000u) | (__float_as_uint(lo) >> 16);
#endif
}

__device__ __forceinline__ unsigned enc_key(float v) {
    unsigned b = __float_as_uint(v);
    return (b & 0x80000000u) ? ~b : (b | 0x80000000u);
}
__device__ __forceinline__ float dec_key(unsigned k) {
    unsigned b = (k & 0x80000000u) ? (k & 0x7fffffffu) : ~k;
    return __uint_as_float(b);
}

// ---------------------------------------------------------------------------
// k_prep: one-time Wg fp32->bf16 (RNE) + zero-init pooled/cnt.
// ---------------------------------------------------------------------------
__global__ __launch_bounds__(256) void k_prep(
    const float* __restrict__ Wg, unsigned short* __restrict__ Wgb,
    unsigned* __restrict__ pooled, unsigned* __restrict__ cnt)
{
    const int g = blockIdx.x * 256 + threadIdx.x;    // 0..4095
    float4 f = *(const float4*)&Wg[g * 4];
    s4v v;
    v[0] = f2b(f.x); v[1] = f2b(f.y); v[2] = f2b(f.z); v[3] = f2b(f.w);
    *(s4v*)&Wgb[g * 4] = v;
    if (g < B * D) pooled[g] = 0u;
    if (g == B * D) *cnt = 0u;
}

// ---------------------------------------------------------------------------
// k_proj: x = lrelu(LN(h@W1^T+b1)) [bf16] ; Wh = x@Wg^T+bg via MFMA (fp32 acc);
// emits WhT bf16 [d][j] + e1,e2 (exp2-domain) fp32.
// Block = 32 rows, 256 threads (4 waves). Grid = 512.
// ---------------------------------------------------------------------------
__global__ __launch_bounds__(256) void k_proj(
    const float* __restrict__ h, const float* __restrict__ W1, const float* __restrict__ b1,
    const unsigned short* __restrict__ Wgb, const float* __restrict__ bg,
    const float* __restrict__ a1, const float* __restrict__ a2,
    unsigned short* __restrict__ WhT, float* __restrict__ e1g, float* __restrict__ e2g)
{
    __shared__ __align__(16) short xep_lds[32 * 136];
    __shared__ __align__(16) short wg_lds[D * 136];
    __shared__ float W1_lds[D * 11];
    __shared__ float h_lds[BR * FIN];
    __shared__ float ep1[2][BR], ep2[2][BR];

    const int t = threadIdx.x;
    const int r0 = blockIdx.x * BR;
    const int bb = r0 >> 11;
    const int jloc = r0 & (N - 1);

    for (int idx = t; idx < D * FIN; idx += 256)
        W1_lds[(idx / FIN) * 11 + (idx % FIN)] = W1[idx];
    for (int idx = t; idx < BR * FIN; idx += 256)
        h_lds[idx] = h[(size_t)r0 * FIN + idx];
    __syncthreads();

    // stage pre-converted Wg bf16 -> LDS (straight copy)
    {
        const int dr = t >> 4;
        const int j8 = t & 15;
        #pragma unroll
        for (int pass = 0; pass < 8; pass++) {
            int dd = pass * 16 + dr;
            *(bf8*)&wg_lds[dd * 136 + j8 * 8] = *(const bf8*)&Wgb[dd * D + j8 * 8];
        }
    }

    // phase 1: fc1 + LN + lrelu — all 8 rows hoisted for ILP
    const int w = t >> 6, lane = t & 63;
    {
        float b1v0 = b1[lane], b1v1 = b1[lane + 64];
        float sA[8], sB[8], smv[8], sqv[8];
        #pragma unroll
        for (int i = 0; i < 8; i++) {
            const float* hr = &h_lds[(w * 8 + i) * FIN];
            float s0 = b1v0, s1 = b1v1;
            #pragma unroll
            for (int k = 0; k < FIN; k++) {
                float hv = hr[k];
                s0 += hv * W1_lds[lane * 11 + k];
                s1 += hv * W1_lds[(lane + 64) * 11 + k];
            }
            sA[i] = s0; sB[i] = s1;
            smv[i] = s0 + s1; sqv[i] = s0 * s0 + s1 * s1;
        }
        #pragma unroll
        for (int m = 1; m <= 32; m <<= 1) {
            #pragma unroll
            for (int i = 0; i < 8; i++) { smv[i] += __shfl_xor(smv[i], m); sqv[i] += __shfl_xor(sqv[i], m); }
        }
        #pragma unroll
        for (int i = 0; i < 8; i++) {
            int r = w * 8 + i;
            float mean = smv[i] * (1.f / D);
            float var  = sqv[i] * (1.f / D) - mean * mean;
            float rs = rsqrtf(var + 1e-5f);
            xep_lds[r * 136 + lane]      = f2b(lrelu((sA[i] - mean) * rs));
            xep_lds[r * 136 + lane + 64] = f2b(lrelu((sB[i] - mean) * rs));
        }
    }
    __syncthreads();

    // phase 2: MFMA  Wh[32][128] = x @ Wg^T
    const int l15 = lane & 15, q = lane >> 4;
    const int mw = w & 1, np = w >> 1;
    f32x4 acc[4];
    #pragma unroll
    for (int nt = 0; nt < 4; nt++)
        #pragma unroll
        for (int r = 0; r < 4; r++) acc[nt][r] = 0.f;

    #pragma unroll
    for (int ks = 0; ks < 4; ks++) {
        bf8 av = *(const bf8*)&xep_lds[(mw * 16 + l15) * 136 + ks * 32 + q * 8];
        #pragma unroll
        for (int nt = 0; nt < 4; nt++) {
            bf8 bv = *(const bf8*)&wg_lds[((np * 4 + nt) * 16 + l15) * 136 + ks * 32 + q * 8];
            acc[nt] = __builtin_amdgcn_mfma_f32_16x16x32_bf16(av, bv, acc[nt], 0, 0, 0);
        }
    }

    // epilogue: +bg, e1/e2 partials
    float e1p[4] = {0.f, 0.f, 0.f, 0.f}, e2p[4] = {0.f, 0.f, 0.f, 0.f};
    #pragma unroll
    for (int nt = 0; nt < 4; nt++) {
        int col = (np * 4 + nt) * 16 + l15;
        float bgv = bg[col], a1v = a1[col], a2v = a2[col];
        #pragma unroll
        for (int r = 0; r < 4; r++) {
            float v = acc[nt][r] + bgv;
            acc[nt][r] = v;
            e1p[r] += v * a1v;
            e2p[r] += v * a2v;
        }
    }
    #pragma unroll
    for (int m = 1; m <= 8; m <<= 1) {
        #pragma unroll
        for (int r = 0; r < 4; r++) { e1p[r] += __shfl_xor(e1p[r], m); e2p[r] += __shfl_xor(e2p[r], m); }
    }
    if (l15 == 0) {
        #pragma unroll
        for (int r = 0; r < 4; r++) {
            ep1[np][mw * 16 + q * 4 + r] = e1p[r];
            ep2[np][mw * 16 + q * 4 + r] = e2p[r];
        }
    }
    __syncthreads();
    if (t < BR) {
        e1g[r0 + t] = (ep1[0][t] + ep1[1][t]) * LOG2E;
        e2g[r0 + t] = (ep2[0][t] + ep2[1][t]) * LOG2E;
    }
    #pragma unroll
    for (int nt = 0; nt < 4; nt++) {
        int col = (np * 4 + nt) * 16 + l15;
        #pragma unroll
        for (int r = 0; r < 4; r++)
            xep_lds[col * 36 + mw * 16 + q * 4 + r] = f2b(acc[nt][r]);
    }
    __syncthreads();
    {
        const int col = t >> 1, jh = (t & 1) * 16;
        unsigned short* dst = WhT + ((size_t)(bb * D + col)) * N + jloc + jh;
        #pragma unroll
        for (int i2 = 0; i2 < 4; i2++)
            *(uint2*)(dst + i2 * 4) = *(const uint2*)&xep_lds[col * 36 + jh + i2 * 4];
    }
}

// ---------------------------------------------------------------------------
// k_attn (R4 structure + depth-2 prefetch): LDS-staged chunks, ones-MFMA for l,
// register ping-pong S0/S1 with 2-chunk lookahead.
// Block = 32 i-rows, 512 threads (8 waves). Grid (N/32, B) = 512.
// Last block (device counter) computes final log_softmax.
// ---------------------------------------------------------------------------
struct Stage {
    int4 a0, a1;      // adj rows 2rg, 2rg+1, cols jq..jq+3
    float4 e2r;       // e2 cols jq..jq+3
    bf8 wr[4];        // WhT rows p*32+dr, cols j8*8..+7
};

__device__ __forceinline__ void load_stage(Stage& s,
        const int* adjp0, const int* adjp1, const float* e2p,
        const unsigned short* whp, int j0) {
    s.a0  = *(const int4*)(adjp0 + j0);
    s.a1  = *(const int4*)(adjp1 + j0);
    s.e2r = *(const float4*)(e2p + j0);
    #pragma unroll
    for (int p = 0; p < 4; p++)
        s.wr[p] = *(const bf8*)(whp + (size_t)p * 32 * N + j0);
}

__device__ __forceinline__ void stage_to_lds(const Stage& s,
        float e1r0, float e1r1, short* pT, short* whT,
        int rg, int jq, int dr, int j8) {
    float t0 = e1r0 + s.e2r.x, t1 = e1r0 + s.e2r.y,
          t2 = e1r0 + s.e2r.z, t3 = e1r0 + s.e2r.w;
    float p0 = s.a0.x ? fexp2(fmaxf(t0, ALPHA * t0)) : 0.f;
    float p1 = s.a0.y ? fexp2(fmaxf(t1, ALPHA * t1)) : 0.f;
    float p2 = s.a0.z ? fexp2(fmaxf(t2, ALPHA * t2)) : 0.f;
    float p3 = s.a0.w ? fexp2(fmaxf(t3, ALPHA * t3)) : 0.f;
    *(uint2*)&pT[(rg * 2) * 136 + jq] = make_uint2(pack2(p0, p1), pack2(p2, p3));

    t0 = e1r1 + s.e2r.x; t1 = e1r1 + s.e2r.y;
    t2 = e1r1 + s.e2r.z; t3 = e1r1 + s.e2r.w;
    p0 = s.a1.x ? fexp2(fmaxf(t0, ALPHA * t0)) : 0.f;
    p1 = s.a1.y ? fexp2(fmaxf(t1, ALPHA * t1)) : 0.f;
    p2 = s.a1.z ? fexp2(fmaxf(t2, ALPHA * t2)) : 0.f;
    p3 = s.a1.w ? fexp2(fmaxf(t3, ALPHA * t3)) : 0.f;
    *(uint2*)&pT[(rg * 2 + 1) * 136 + jq] = make_uint2(pack2(p0, p1), pack2(p2, p3));

    #pragma unroll
    for (int p = 0; p < 4; p++)
        *(bf8*)&whT[(p * 32 + dr) * 136 + j8 * 8] = s.wr[p];
}

__global__ __launch_bounds__(512, 4) void k_attn(
    const int* __restrict__ adj, const unsigned short* __restrict__ WhT,
    const float* __restrict__ e1g, const float* __restrict__ e2g,
    unsigned* __restrict__ pooled, unsigned* __restrict__ cnt,
    const float* __restrict__ W2, const float* __restrict__ b2,
    float* __restrict__ out)
{
    __shared__ __align__(16) short pT[TI * 136];     // A-op: [i][k=j], pad 8
    __shared__ __align__(16) short whT[D * 136];     // B-op: [d][k=j], pad 8
    __shared__ float statsp[4][TI][2];
    __shared__ float maxb[2][D];
    __shared__ int finalflag;

    const int t = threadIdx.x;
    const int b = blockIdx.y;
    const int i0 = blockIdx.x * TI;

    const int w = t >> 6, lane = t & 63;
    const int l15 = lane & 15, q = lane >> 4;
    const int mw = w & 1;          // m-tile (0/1)
    const int np = w >> 1;         // n-quarter (0..3)

    // staging maps
    const int rg = t >> 5;                 // 0..15 -> rows {2rg, 2rg+1}
    const int jq = (t & 31) * 4;           // j offset within chunk
    const int dr = t >> 4;                 // 0..31 (whT rows per pass)
    const int j8 = t & 15;                 // 16B granule within chunk

    const float e1r0 = e1g[b * N + i0 + rg * 2];       // exp2-domain
    const float e1r1 = e1g[b * N + i0 + rg * 2 + 1];

    const unsigned short* WhTb = WhT + (size_t)b * D * N;
    const int* adjp0 = adj + ((size_t)b * N + i0 + rg * 2) * N + jq;
    const int* adjp1 = adjp0 + N;
    const float* e2p = e2g + b * N + jq;
    const unsigned short* whp = WhTb + (size_t)dr * N + j8 * 8;

    f32x4 acc[2], accl;
    #pragma unroll
    for (int nt = 0; nt < 2; nt++)
        #pragma unroll
        for (int r = 0; r < 4; r++) acc[nt][r] = 0.f;
    #pragma unroll
    for (int r = 0; r < 4; r++) accl[r] = 0.f;

    bf8 ones;
    #pragma unroll
    for (int i = 0; i < 8; i++) ones[i] = (short)0x3F80;   // bf16(1.0)

    Stage S0, S1;
    load_stage(S0, adjp0, adjp1, e2p, whp, 0);
    load_stage(S1, adjp0, adjp1, e2p, whp, JC);

    #define MFMA_PHASE() do {                                                        \
        _Pragma("unroll")                                                            \
        for (int ks = 0; ks < 4; ks++) {                                             \
            bf8 av = *(const bf8*)&pT[(mw * 16 + l15) * 136 + ks * 32 + q * 8];      \
            _Pragma("unroll")                                                        \
            for (int nt = 0; nt < 2; nt++) {                                         \
                bf8 bv = *(const bf8*)&whT[((np * 2 + nt) * 16 + l15) * 136 + ks * 32 + q * 8]; \
                acc[nt] = __builtin_amdgcn_mfma_f32_16x16x32_bf16(av, bv, acc[nt], 0, 0, 0);    \
            }                                                                        \
            accl = __builtin_amdgcn_mfma_f32_16x16x32_bf16(av, ones, accl, 0, 0, 0); \
        }                                                                            \
    } while (0)

    for (int c = 0; c < N / JC; c += 2) {
        // even chunk: consume S0
        stage_to_lds(S0, e1r0, e1r1, pT, whT, rg, jq, dr, j8);
        __syncthreads();
        if (c + 2 < N / JC) load_stage(S0, adjp0, adjp1, e2p, whp, (c + 2) * JC);
        MFMA_PHASE();
        __syncthreads();
        // odd chunk: consume S1
        stage_to_lds(S1, e1r0, e1r1, pT, whT, rg, jq, dr, j8);
        __syncthreads();
        if (c + 3 < N / JC) load_stage(S1, adjp0, adjp1, e2p, whp, (c + 3) * JC);
        MFMA_PHASE();
        __syncthreads();
    }
    #undef MFMA_PHASE

    // epilogue: /l -> LN stats (cross-np via LDS) -> lrelu -> max-pool
    float smr[4] = {0.f, 0.f, 0.f, 0.f}, sqr[4] = {0.f, 0.f, 0.f, 0.f};
    #pragma unroll
    for (int r = 0; r < 4; r++) {
        float rinv = 1.f / accl[r];
        #pragma unroll
        for (int nt = 0; nt < 2; nt++) {
            float v = acc[nt][r] * rinv;
            acc[nt][r] = v;
            smr[r] += v;
            sqr[r] += v * v;
        }
    }
    #pragma unroll
    for (int m = 1; m <= 8; m <<= 1) {
        #pragma unroll
        for (int r = 0; r < 4; r++) { smr[r] += __shfl_xor(smr[r], m); sqr[r] += __shfl_xor(sqr[r], m); }
    }
    if (l15 == 0) {
        #pragma unroll
        for (int r = 0; r < 4; r++) {
            statsp[np][mw * 16 + q * 4 + r][0] = smr[r];
            statsp[np][mw * 16 + q * 4 + r][1] = sqr[r];
        }
    }
    __syncthreads();

    float mx[2] = {-1e30f, -1e30f};
    #pragma unroll
    for (int r = 0; r < 4; r++) {
        int row = mw * 16 + q * 4 + r;
        float s0 = statsp[0][row][0] + statsp[1][row][0] + statsp[2][row][0] + statsp[3][row][0];
        float s1 = statsp[0][row][1] + statsp[1][row][1] + statsp[2][row][1] + statsp[3][row][1];
        float mean = s0 * (1.f / D);
        float var  = s1 * (1.f / D) - mean * mean;
        float rs = rsqrtf(var + 1e-5f);
        #pragma unroll
        for (int nt = 0; nt < 2; nt++) {
            float v = lrelu((acc[nt][r] - mean) * rs);
            mx[nt] = fmaxf(mx[nt], v);
        }
    }
    #pragma unroll
    for (int m = 16; m <= 32; m <<= 1) {
        #pragma unroll
        for (int nt = 0; nt < 2; nt++) mx[nt] = fmaxf(mx[nt], __shfl_xor(mx[nt], m));
    }
    if (q == 0) {
        #pragma unroll
        for (int nt = 0; nt < 2; nt++) maxb[mw][(np * 2 + nt) * 16 + l15] = mx[nt];
    }
    __syncthreads();
    if (t < D) {
        float v = fmaxf(maxb[0][t], maxb[1][t]);
        atomicMax(&pooled[b * D + t], enc_key(v));
    }
    __syncthreads();           // all this block's atomics issued

    // completion counter; last block does final 128->2 matmul + log_softmax
    if (t == 0) {
        __threadfence();
        unsigned old = atomicAdd(cnt, 1u);
        finalflag = (old == NBLK_ATTN - 1) ? 1 : 0;
    }
    __syncthreads();
    if (finalflag && t < 256) {
        const int fb = t >> 5;
        const int fq = t & 31;
        float s0 = 0.f, s1 = 0.f;
        #pragma unroll
        for (int m = 0; m < 4; m++) {
            int dd = fq + 32 * m;
            unsigned key = __hip_atomic_load(&pooled[fb * D + dd], __ATOMIC_RELAXED,
                                             __HIP_MEMORY_SCOPE_AGENT);
            float v = dec_key(key);
            s0 += v * W2[dd];
            s1 += v * W2[D + dd];
        }
        #pragma unroll
        for (int m = 1; m <= 16; m <<= 1) { s0 += __shfl_xor(s0, m); s1 += __shfl_xor(s1, m); }
        if (fq == 0) {
            float o0 = s0 + b2[0], o1 = s1 + b2[1];
            float mxv = fmaxf(o0, o1);
            float ls = logf(__expf(o0 - mxv) + __expf(o1 - mxv));
            out[fb * 2 + 0] = o0 - mxv - ls;
            out[fb * 2 + 1] = o1 - mxv - ls;
        }
    }
}

extern "C" void kernel_launch(void* const* d_in, const int* in_sizes, int n_in,
                              void* d_out, int out_size, void* d_ws, size_t ws_size,
                              hipStream_t stream) {
    const float* h   = (const float*)d_in[0];
    const int*   adj = (const int*)d_in[1];
    const float* W1  = (const float*)d_in[2];
    const float* b1  = (const float*)d_in[3];
    const float* Wg  = (const float*)d_in[4];
    const float* bg  = (const float*)d_in[5];
    const float* a1  = (const float*)d_in[6];
    const float* a2  = (const float*)d_in[7];
    const float* W2  = (const float*)d_in[8];
    const float* b2  = (const float*)d_in[9];
    float* out = (float*)d_out;

    unsigned short* WhT = (unsigned short*)d_ws;                       // B*D*N bf16
    float* e1g = (float*)((char*)d_ws + (size_t)B * D * N * 2);        // B*N f32
    float* e2g = e1g + (size_t)B * N;                                  // B*N f32
    unsigned* pooled = (unsigned*)(e2g + (size_t)B * N);               // B*D u32
    unsigned* cnt = pooled + (size_t)B * D;                            // 1 u32
    unsigned short* Wgb = (unsigned short*)(cnt + 4);                  // D*D bf16

    k_prep<<<16, 256, 0, stream>>>(Wg, Wgb, pooled, cnt);
    k_proj<<<(B * N) / BR, 256, 0, stream>>>(h, W1, b1, Wgb, bg, a1, a2,
                                             WhT, e1g, e2g);
    k_attn<<<dim3(N / TI, B), 512, 0, stream>>>(adj, WhT, e1g, e2g, pooled, cnt,
                                                W2, b2, out);
}